// Round 2
// baseline (186.975 us; speedup 1.0000x reference)
//
#include <hip/hip_runtime.h>

#define RESO 128

// ---------------------------------------------------------------------------
// Kernel 1: prefix scans over the three 128-element layers.
// a3[i] = off0 + sum_{j<=i} t[j],  t[0]=0, t[i]=2*L[i-1]+2*L[i]
// a6[i] = sum_{j<=i} s[j],         s[0]=0, s[i]=3*L[i-1]+L[i]+2*a3[i-1]
// One block of 128 threads (2 waves); shuffle-based inclusive scans.
// ws layout: [0:128)=xA3 [128:256)=yA4 [256:384)=zA5
//            [384:512)=xA6 [512:640)=yA6 [640:768)=zA6
// ---------------------------------------------------------------------------
__global__ __launch_bounds__(128) void scan_kernel(
    const float* __restrict__ xL, const float* __restrict__ yL,
    const float* __restrict__ zL, const float* __restrict__ off,
    float* __restrict__ ws)
{
    __shared__ float s_wave[4];
    __shared__ float s_a3[RESO];

    const int tid  = threadIdx.x;
    const int lane = tid & 63;
    const int wave = tid >> 6;

    const float* layers[3] = {xL, yL, zL};

    for (int ax = 0; ax < 3; ++ax) {
        const float* L = layers[ax];
        const float li   = L[tid];
        const float lim1 = (tid > 0) ? L[tid - 1] : 0.0f;

        // ---- scan 1: a3 ----
        float v = (tid == 0) ? 0.0f : 2.0f * lim1 + 2.0f * li;
        #pragma unroll
        for (int o = 1; o < 64; o <<= 1) {
            float u = __shfl_up(v, o, 64);
            if (lane >= o) v += u;
        }
        if (lane == 63) s_wave[wave] = v;
        __syncthreads();
        if (wave == 1) v += s_wave[0];
        const float a3 = off[ax] + v;
        s_a3[tid] = a3;
        __syncthreads();

        // ---- scan 2: a6 (consumes a3[i-1]) ----
        const float a3m1 = (tid > 0) ? s_a3[tid - 1] : 0.0f;
        float w = (tid == 0) ? 0.0f : 3.0f * lim1 + li + 2.0f * a3m1;
        #pragma unroll
        for (int o = 1; o < 64; o <<= 1) {
            float u = __shfl_up(w, o, 64);
            if (lane >= o) w += u;
        }
        if (lane == 63) s_wave[2 + wave] = w;
        __syncthreads();
        if (wave == 1) w += s_wave[2];

        ws[ax * RESO + tid]       = a3;
        ws[(3 + ax) * RESO + tid] = w;
        __syncthreads();  // protect s_wave/s_a3 reuse next axis
    }
}

// ---------------------------------------------------------------------------
// Kernel 2: sdf pass.  out[i] = num/den/reso
// ---------------------------------------------------------------------------
__global__ __launch_bounds__(256) void sdf_kernel(
    const float* __restrict__ pts, const int* __restrict__ idx,
    const float* __restrict__ xL, const float* __restrict__ yL,
    const float* __restrict__ zL, const float* __restrict__ ws,
    const float* __restrict__ off, float* __restrict__ out, int N)
{
    __shared__ float tab[9][RESO];
    const int tid = threadIdx.x;
    if (tid < RESO) {
        tab[0][tid] = xL[tid];
        tab[1][tid] = yL[tid];
        tab[2][tid] = zL[tid];
        #pragma unroll
        for (int k = 0; k < 6; ++k) tab[3 + k][tid] = ws[k * RESO + tid];
    }
    __syncthreads();

    const int i = blockIdx.x * blockDim.x + tid;
    if (i >= N) return;

    const float off3 = off[3];
    const int id = idx[i];
    const int iz = id & 127;
    const int iy = (id >> 7) & 127;
    const int ix = (id >> 14) & 127;

    const float px = pts[3 * i + 0];
    const float py = pts[3 * i + 1];
    const float pz = pts[3 * i + 2];

    const float a0 = tab[0][iz] * px;
    const float a1 = tab[1][iy] * py;
    const float a2 = tab[2][ix] * pz;
    const float a3 = tab[3][iz];
    const float a4 = tab[4][iy];
    const float a5 = tab[5][ix];
    const float a6 = off3 + tab[6][iz] + tab[7][iy] + tab[8][ix];

    const float num = (a0 + a3) * px + (a1 + a4) * py + (a2 + a5) * pz + a6;
    const float dx = 2.0f * a0 + a3;
    const float dy = 2.0f * a1 + a4;
    const float dz = 2.0f * a2 + a5;
    const float den = sqrtf(dx * dx + dy * dy + dz * dz);

    out[i] = num / den / (float)RESO;
}

// ---------------------------------------------------------------------------
// Kernel 3: render/normal pass. out3[3i..3i+2] = n / max(|n|, 1e-12)
// ---------------------------------------------------------------------------
__global__ __launch_bounds__(256) void render_kernel(
    const float* __restrict__ pts, const int* __restrict__ idx,
    const float* __restrict__ xL, const float* __restrict__ yL,
    const float* __restrict__ zL, const float* __restrict__ ws,
    float* __restrict__ out3, int N)
{
    __shared__ float tab[6][RESO];
    const int tid = threadIdx.x;
    if (tid < RESO) {
        tab[0][tid] = xL[tid];
        tab[1][tid] = yL[tid];
        tab[2][tid] = zL[tid];
        #pragma unroll
        for (int k = 0; k < 3; ++k) tab[3 + k][tid] = ws[k * RESO + tid];
    }
    __syncthreads();

    const int i = blockIdx.x * blockDim.x + tid;
    if (i >= N) return;

    const int id = idx[i];
    const int jz = id & 127;
    const int jy = (id >> 7) & 127;
    const int jx = (id >> 14) & 127;

    const float rx = pts[3 * i + 0];
    const float ry = pts[3 * i + 1];
    const float rz = pts[3 * i + 2];

    const float nx = 2.0f * tab[0][jz] * rx + tab[3][jz];
    const float ny = 2.0f * tab[1][jy] * ry + tab[4][jy];
    const float nz = 2.0f * tab[2][jx] * rz + tab[5][jx];

    const float norm = sqrtf(nx * nx + ny * ny + nz * nz);
    const float d = fmaxf(norm, 1e-12f);

    out3[3 * i + 0] = nx / d;
    out3[3 * i + 1] = ny / d;
    out3[3 * i + 2] = nz / d;
}

// ---------------------------------------------------------------------------
// Inputs (setup_inputs order):
//  0 renderPointList (N*3 f32)   1 renderIndexList (N i32)
//  2 sdfPointList    (N*3 f32)   3 sdfIndexList    (N i32)
//  4 xLayer (128 f32) 5 yLayer (128 f32) 6 zLayer (128 f32) 7 offset (4 f32)
// Output: sdfList (N f32) ++ normalList (N*3 f32)
// ---------------------------------------------------------------------------
extern "C" void kernel_launch(void* const* d_in, const int* in_sizes, int n_in,
                              void* d_out, int out_size, void* d_ws, size_t ws_size,
                              hipStream_t stream)
{
    const float* renderPts = (const float*)d_in[0];
    const int*   renderIdx = (const int*)d_in[1];
    const float* sdfPts    = (const float*)d_in[2];
    const int*   sdfIdx    = (const int*)d_in[3];
    const float* xL        = (const float*)d_in[4];
    const float* yL        = (const float*)d_in[5];
    const float* zL        = (const float*)d_in[6];
    const float* off       = (const float*)d_in[7];

    float* ws  = (float*)d_ws;
    float* out = (float*)d_out;

    const int N = in_sizes[1];  // renderIndexList element count

    scan_kernel<<<1, 128, 0, stream>>>(xL, yL, zL, off, ws);

    const int block = 256;
    const int grid = (N + block - 1) / block;
    sdf_kernel<<<grid, block, 0, stream>>>(sdfPts, sdfIdx, xL, yL, zL, ws, off, out, N);
    render_kernel<<<grid, block, 0, stream>>>(renderPts, renderIdx, xL, yL, zL, ws, out + N, N);
}